// Round 12
// baseline (123.066 us; speedup 1.0000x reference)
//
#include <hip/hip_runtime.h>
#include <hip/hip_bf16.h>

#define B_ 4
#define N_ 1024
#define M_ 32
#define C_ 128
#define D_ 64
#define BM_ (B_*M_)   // 128 independent attention problems

typedef float f32x4 __attribute__((ext_vector_type(4)));
typedef float f32x16 __attribute__((ext_vector_type(16)));
typedef short short8 __attribute__((ext_vector_type(8)));
typedef short short4v __attribute__((ext_vector_type(4)));

#define EXP2(x) __builtin_amdgcn_exp2f(x)

static __device__ __forceinline__ int cvtpk_bf16(float lo, float hi) {
  int r;
  asm volatile("v_cvt_pk_bf16_f32 %0, %1, %2" : "=v"(r) : "v"(lo), "v"(hi));
  return r;
}
static __device__ __forceinline__ void plswap(int& a, int& b) {
  asm volatile("v_permlane32_swap_b32 %0, %1" : "+v"(a), "+v"(b));
}

// ---------------------------------------------------------------------------
// Kernel 0: transpose weights to bf16, concatenated [256 cols][128 k].
// cols 0-63 = w_q scaled by (1/sqrt(64))*log2(e), 64-127 = w_k, 128-255 = w_v.
// ---------------------------------------------------------------------------
__global__ __launch_bounds__(256) void prep_weights(
    const float* __restrict__ wq, const float* __restrict__ wk,
    const float* __restrict__ wv, __hip_bfloat16* __restrict__ wt) {
  int idx = blockIdx.x * 256 + threadIdx.x;   // 0 .. 32767
  int col = idx >> 7;      // 0..255
  int kk  = idx & 127;     // 0..127
  float v;
  if (col < 64)        v = wq[kk * 64 + col] * (0.125f * 1.44269504088896f);
  else if (col < 128)  v = wk[kk * 64 + (col - 64)];
  else                 v = wv[kk * 128 + (col - 128)];
  wt[col * 128 + kk] = __float2bfloat16(v);
}

// ---------------------------------------------------------------------------
// Kernel 1: LayerNorm (register-based) + Q/K/V projections via MFMA.
// Grid: 128 (b,m) * 8 row-tiles of 128. Block: 512 threads (8 waves).
// ---------------------------------------------------------------------------
__global__ __launch_bounds__(512, 6) void ln_qkv(
    const float* __restrict__ x, const float* __restrict__ gamma,
    const float* __restrict__ beta, const __hip_bfloat16* __restrict__ wt,
    __hip_bfloat16* __restrict__ q, __hip_bfloat16* __restrict__ k,
    __hip_bfloat16* __restrict__ vt) {
  __shared__ alignas(16) __hip_bfloat16 xn[128][136];  // 34.8 KB

  int bid = blockIdx.x;
  int bm  = bid >> 3;
  int n0  = (bid & 7) * 128;
  int b   = bm >> 5, m = bm & 31;
  int tid = threadIdx.x;

  const float* xbase = x + ((((size_t)b * N_ + n0) * M_ + m) * C_);
  int c4 = tid & 31;
  float4 vch[8];
  #pragma unroll
  for (int it = 0; it < 8; ++it) {
    int r = (it * 512 + tid) >> 5;
    vch[it] = *reinterpret_cast<const float4*>(xbase + (size_t)r * (M_ * C_) + c4 * 4);
  }
  float4 g4 = *reinterpret_cast<const float4*>(gamma + c4 * 4);
  float4 b4 = *reinterpret_cast<const float4*>(beta + c4 * 4);

  #pragma unroll
  for (int it = 0; it < 8; ++it) {
    int r = (it * 512 + tid) >> 5;
    float4 v = vch[it];
    float s  = (v.x + v.y) + (v.z + v.w);
    float sq = (v.x * v.x + v.y * v.y) + (v.z * v.z + v.w * v.w);
    s  += __shfl_xor(s, 1);  sq += __shfl_xor(sq, 1);
    s  += __shfl_xor(s, 2);  sq += __shfl_xor(sq, 2);
    s  += __shfl_xor(s, 4);  sq += __shfl_xor(sq, 4);
    s  += __shfl_xor(s, 8);  sq += __shfl_xor(sq, 8);
    s  += __shfl_xor(s, 16); sq += __shfl_xor(sq, 16);
    float mean = s * (1.f / 128.f);
    float var  = sq * (1.f / 128.f) - mean * mean;
    float rstd = rsqrtf(var + 1e-3f);
    alignas(8) __hip_bfloat16 tmp[4];
    tmp[0] = __float2bfloat16((v.x - mean) * rstd * g4.x + b4.x);
    tmp[1] = __float2bfloat16((v.y - mean) * rstd * g4.y + b4.y);
    tmp[2] = __float2bfloat16((v.z - mean) * rstd * g4.z + b4.z);
    tmp[3] = __float2bfloat16((v.w - mean) * rstd * g4.w + b4.w);
    *reinterpret_cast<short4v*>(&xn[r][c4 * 4]) =
        *reinterpret_cast<const short4v*>(tmp);
  }
  __syncthreads();

  int w = tid >> 6, l = tid & 63, lr = l & 15, lh = l >> 4;
  int ct0 = w, ct1 = w + 8;

  short8 wf0[4], wf1[4];
  #pragma unroll
  for (int h = 0; h < 4; ++h) {
    wf0[h] = *reinterpret_cast<const short8*>(
        &wt[(ct0 * 16 + lr) * 128 + h * 32 + lh * 8]);
    wf1[h] = *reinterpret_cast<const short8*>(
        &wt[(ct1 * 16 + lr) * 128 + h * 32 + lh * 8]);
  }

  const f32x4 fzero = {0.f, 0.f, 0.f, 0.f};
  int col0 = ct0 * 16 + lr;
  int cV   = w * 16 + lr;
  #pragma unroll
  for (int rt = 0; rt < 8; ++rt) {
    short8 a[4];
    #pragma unroll
    for (int h = 0; h < 4; ++h)
      a[h] = *reinterpret_cast<const short8*>(&xn[rt * 16 + lr][h * 32 + lh * 8]);
    f32x4 acc0 = fzero, acc1 = fzero;
    #pragma unroll
    for (int h = 0; h < 4; ++h) {
      acc0 = __builtin_amdgcn_mfma_f32_16x16x32_bf16(a[h], wf0[h], acc0, 0, 0, 0);
      acc1 = __builtin_amdgcn_mfma_f32_16x16x32_bf16(a[h], wf1[h], acc1, 0, 0, 0);
    }
    int nb = n0 + rt * 16 + lh * 4;
    if (ct0 < 4) {
      #pragma unroll
      for (int r = 0; r < 4; ++r)
        q[((size_t)bm * N_ + nb + r) * D_ + col0] = __float2bfloat16(acc0[r]);
    } else {
      #pragma unroll
      for (int r = 0; r < 4; ++r)
        k[((size_t)bm * N_ + nb + r) * D_ + (col0 - 64)] = __float2bfloat16(acc0[r]);
    }
    alignas(8) __hip_bfloat16 tmp[4];
    #pragma unroll
    for (int r = 0; r < 4; ++r) tmp[r] = __float2bfloat16(acc1[r]);
    *reinterpret_cast<short4v*>(&vt[((size_t)bm * C_ + cV) * N_ + nb]) =
        *reinterpret_cast<const short4v*>(tmp);
  }
}

// ---------------------------------------------------------------------------
// Kernel 2: flash attention, KVBLK=32, delayed-PV pipeline. Halving the KV
// tile cuts per-wave register state (~40 VGPR) so VGPR+AGPR <= 170 and the
// THIRD block per CU fits (waves arrive per-block: waves/SIMD = blocks/CU).
// K double-buffered (stride 72), V triple-buffered (stride 40, conflict-free
// per 8-lane bank model). Speculative softmax. One barrier per tile.
// LDS 39936 B. Grid 1024, XCD-swizzled. Block 256 = 4 waves x 32 q-rows.
// ---------------------------------------------------------------------------
__global__ __launch_bounds__(256, 3) void attn_kernel(
    const float* __restrict__ x, const float* __restrict__ lam,
    const __hip_bfloat16* __restrict__ q, const __hip_bfloat16* __restrict__ k,
    const __hip_bfloat16* __restrict__ vt, float* __restrict__ out) {
  __shared__ alignas(16) __hip_bfloat16 kbuf[2][32 * 72];   // 4608 B each
  __shared__ alignas(16) __hip_bfloat16 vbuf[3][128 * 40];  // 10240 B each

  int h   = blockIdx.x;
  int s_  = h >> 3;
  int bm  = (s_ >> 3) * 8 + (h & 7);
  int n0  = (s_ & 7) * 128;
  int b   = bm >> 5, m = bm & 31;
  int tid = threadIdx.x;
  int w = tid >> 6, l = tid & 63;
  int lq = l & 31, hi = l >> 5;

  const __hip_bfloat16* kbase = k + (size_t)bm * N_ * D_;
  const __hip_bfloat16* vbase = vt + (size_t)bm * C_ * N_;

  // staging chunk coords (16B chunks): K 32x64 -> 1 chunk/thread,
  // V 128x32 -> 2 chunks/thread
  int kr = tid >> 3, kc = tid & 7;
  int vr[2], vc = tid & 3;
  #pragma unroll
  for (int i = 0; i < 2; ++i) vr[i] = (tid + i * 256) >> 2;

  // Q fragments (B operand of S^T): lane = col q, k = d = 16*s + 8*hi + i
  short8 qf[4];
  {
    int n = n0 + w * 32 + lq;
    const __hip_bfloat16* qp = q + ((size_t)bm * N_ + n) * D_;
    #pragma unroll
    for (int s = 0; s < 4; ++s)
      qf[s] = *reinterpret_cast<const short8*>(qp + s * 16 + hi * 8);
  }

  f32x16 acc[4];
  const f32x16 z16 = {0.f,0.f,0.f,0.f,0.f,0.f,0.f,0.f,
                      0.f,0.f,0.f,0.f,0.f,0.f,0.f,0.f};
  #pragma unroll
  for (int ct = 0; ct < 4; ++ct) acc[ct] = z16;
  float m_run = 0.f, l_run = 0.f;   // spec-softmax: shift-invariant, gate at +8

  union W4 { int w[4]; short8 s8; } pf[2];   // P fragments, live across iters
  short8 kreg, vreg[2];

  // ---- prologue: stage tile 0 (K -> kbuf[0], V -> vbuf[0]) ----
  kreg = *reinterpret_cast<const short8*>(&kbase[(size_t)kr * D_ + kc * 8]);
  #pragma unroll
  for (int i = 0; i < 2; ++i)
    vreg[i] = *reinterpret_cast<const short8*>(&vbase[(size_t)vr[i] * N_ + vc * 8]);
  *reinterpret_cast<short8*>(&kbuf[0][kr * 72 + kc * 8]) = kreg;
  #pragma unroll
  for (int i = 0; i < 2; ++i)
    *reinterpret_cast<short8*>(&vbuf[0][vr[i] * 40 + vc * 8]) = vreg[i];
  __syncthreads();

  for (int t = 0; t < 32; ++t) {
    int kcur = t & 1, knxt = kcur ^ 1;
    int vw  = (t + 1) % 3;         // V slot being written (tile t+1)
    int vrd = (t + 2) % 3;         // V slot of tile t-1 (== (t-1)%3)

    // ---- issue next tile's global loads ----
    if (t < 31) {
      int j0n = (t + 1) * 32;
      kreg = *reinterpret_cast<const short8*>(&kbase[(size_t)(j0n + kr) * D_ + kc * 8]);
      #pragma unroll
      for (int i = 0; i < 2; ++i)
        vreg[i] = *reinterpret_cast<const short8*>(&vbase[(size_t)vr[i] * N_ + j0n + vc * 8]);
    }

    const __hip_bfloat16* kt = kbuf[kcur];

    // ---- QK^T(t): S^T = K * Q^T (32 kj x 32 q, one output tile) ----
    f32x16 st = z16;
    #pragma unroll
    for (int s = 0; s < 4; ++s) {
      short8 kf = *reinterpret_cast<const short8*>(&kt[lq * 72 + s * 16 + hi * 8]);
      st = __builtin_amdgcn_mfma_f32_32x32x16_bf16(kf, qf[s], st, 0, 0, 0);
    }

    // ---- PV(t-1): independent MFMA stream, overlaps softmax(t) VALU ----
    if (t > 0) {
      const __hip_bfloat16* vtt = vbuf[vrd];
      #pragma unroll
      for (int kb = 0; kb < 2; ++kb) {
        #pragma unroll
        for (int ct = 0; ct < 4; ++ct) {
          short8 vf = *reinterpret_cast<const short8*>(
              &vtt[(ct * 32 + lq) * 40 + kb * 16 + hi * 8]);
          acc[ct] = __builtin_amdgcn_mfma_f32_32x32x16_bf16(pf[kb].s8, vf, acc[ct], 0, 0, 0);
        }
      }
    }

    // ---- max tree (VALU, overlaps PV execution) ----
    float mx;
    {
      float t4[4];
      #pragma unroll
      for (int i = 0; i < 4; ++i)
        t4[i] = fmaxf(fmaxf(st[i], st[i + 4]), fmaxf(st[i + 8], st[i + 12]));
      mx = fmaxf(fmaxf(t4[0], t4[1]), fmaxf(t4[2], t4[3]));
      mx = fmaxf(mx, __shfl_xor(mx, 32));
    }

    // ---- speculative exp with OLD m_run (TRANS pipe; shift-invariant) ----
    #pragma unroll
    for (int i = 0; i < 16; ++i) st[i] = EXP2(st[i] - m_run);

    // ---- rare correction: max grew past THR=8 ----
    if (__any(mx > m_run + 8.0f)) {
      float mnew = fmaxf(m_run, mx);
      float fac = EXP2(m_run - mnew);
      m_run = mnew;
      l_run *= fac;
      #pragma unroll
      for (int i = 0; i < 16; ++i) st[i] *= fac;
      #pragma unroll
      for (int reg = 0; reg < 16; ++reg) {
        int qi = (reg & 3) + 8 * (reg >> 2) + 4 * hi;
        float f = __shfl(fac, qi);
        #pragma unroll
        for (int ct = 0; ct < 4; ++ct) acc[ct][reg] *= f;
      }
    }

    // ---- build PV A-fragments for tile t (consumed next iteration) ----
    {
      int A  = cvtpk_bf16(st[0],  st[1]);
      int Bw = cvtpk_bf16(st[2],  st[3]);
      int Cw = cvtpk_bf16(st[4],  st[5]);
      int Dw = cvtpk_bf16(st[6],  st[7]);
      plswap(A, Cw);
      plswap(Bw, Dw);
      pf[0].w[0] = A;  pf[0].w[1] = Bw;
      pf[0].w[2] = Cw; pf[0].w[3] = Dw;
      int E = cvtpk_bf16(st[8],  st[9]);
      int F = cvtpk_bf16(st[10], st[11]);
      int G = cvtpk_bf16(st[12], st[13]);
      int H = cvtpk_bf16(st[14], st[15]);
      plswap(E, G);
      plswap(F, H);
      pf[1].w[0] = E; pf[1].w[1] = F;
      pf[1].w[2] = G; pf[1].w[3] = H;
    }

    // ---- l sum tree (VALU; overlaps PV execution) ----
    {
      float s4[4];
      #pragma unroll
      for (int i = 0; i < 4; ++i)
        s4[i] = (st[i] + st[i + 4]) + (st[i + 8] + st[i + 12]);
      float rs = (s4[0] + s4[1]) + (s4[2] + s4[3]);
      rs += __shfl_xor(rs, 32);
      l_run += rs;
    }

    // ---- stage tile t+1 into kbuf[knxt], vbuf[vw]; one barrier per tile ----
    if (t < 31) {
      *reinterpret_cast<short8*>(&kbuf[knxt][kr * 72 + kc * 8]) = kreg;
      #pragma unroll
      for (int i = 0; i < 2; ++i)
        *reinterpret_cast<short8*>(&vbuf[vw][vr[i] * 40 + vc * 8]) = vreg[i];
      __syncthreads();
    }
  }

  // ---- final PV(31): V(31) written at t=30 into slot 31%3 = 1 ----
  {
    const __hip_bfloat16* vtt = vbuf[1];
    #pragma unroll
    for (int kb = 0; kb < 2; ++kb) {
      #pragma unroll
      for (int ct = 0; ct < 4; ++ct) {
        short8 vf = *reinterpret_cast<const short8*>(
            &vtt[(ct * 32 + lq) * 40 + kb * 16 + hi * 8]);
        acc[ct] = __builtin_amdgcn_mfma_f32_32x32x16_bf16(pf[kb].s8, vf, acc[ct], 0, 0, 0);
      }
    }
  }

  // ---- epilogue: out = x + (O / l) * lam ----
  float inv = 1.0f / l_run;
  float rlv[16];
  #pragma unroll
  for (int reg = 0; reg < 16; ++reg) {
    int qi = (reg & 3) + 8 * (reg >> 2) + 4 * hi;
    rlv[reg] = __shfl(inv, qi);
  }
  #pragma unroll
  for (int ct = 0; ct < 4; ++ct) {
    int c = ct * 32 + lq;
    float lamc = lam[c];
    #pragma unroll
    for (int reg = 0; reg < 16; ++reg) {
      int qi = (reg & 3) + 8 * (reg >> 2) + 4 * hi;
      int n = n0 + w * 32 + qi;
      size_t idx = ((((size_t)b * N_ + n) * M_ + m) * C_) + c;
      out[idx] = x[idx] + acc[ct][reg] * rlv[reg] * lamc;
    }
  }
}

// ---------------------------------------------------------------------------
extern "C" void kernel_launch(void* const* d_in, const int* in_sizes, int n_in,
                              void* d_out, int out_size, void* d_ws, size_t ws_size,
                              hipStream_t stream) {
  const float* x     = (const float*)d_in[0];
  const float* gamma = (const float*)d_in[1];
  const float* beta  = (const float*)d_in[2];
  const float* wq    = (const float*)d_in[3];
  const float* wk    = (const float*)d_in[4];
  const float* wv    = (const float*)d_in[5];
  const float* lam   = (const float*)d_in[6];
  float* out = (float*)d_out;

  __hip_bfloat16* ws = (__hip_bfloat16*)d_ws;
  __hip_bfloat16* wt = ws;                        // 256*128
  __hip_bfloat16* q  = wt + 256 * 128;            // 128*1024*64
  __hip_bfloat16* k  = q + (size_t)BM_ * N_ * D_; // 128*1024*64
  __hip_bfloat16* vt = k + (size_t)BM_ * N_ * D_; // 128*128*1024 (transposed)

  prep_weights<<<128, 256, 0, stream>>>(wq, wk, wv, wt);
  ln_qkv<<<BM_ * (N_ / 128), 512, 0, stream>>>(x, gamma, beta, wt, q, k, vt);
  attn_kernel<<<BM_ * (N_ / 128), 256, 0, stream>>>(x, lam, q, k, vt, out);
}